// Round 8
// baseline (25.382 us; speedup 1.0000x reference)
//
#include <hip/hip_runtime.h>
#include <math.h>

#define NN 2048
#define RR 10
#define MM 2048
#define CC 84
#define IEPS 1e-7f
#define FINF 0x7fffffff

// Single fused kernel, register-blocked GG=4.
// Block b -> n-group g = (b*171)&511 (bijection; mixes long/short scans
// across CUs). Block = 640 threads = 10 waves; wave r scans dpreds[r] once
// for the 4 preds n = 4g..4g+3 (one float4 load per 64-m chunk, corners
// computed once, 4 tests). First-hit per n = min over chunks of
// (ballot ? m0+ffs-1 : INF) -- SALU, branchless, == argmax-of-bool.
// Early exit when all 4 found. Results via LDS; waves 0..3 run the
// entropy/softmax epilogue for their n.
// Division-free IoU: inter/(a1+a2-inter+eps) > 0.5 <=> 3*inter > a1+a2+eps.
__global__ __launch_bounds__(640) void fused_kernel(
    const float* __restrict__ pred,
    const float* __restrict__ dpreds,
    const float* __restrict__ confs,
    float* __restrict__ out) {
  __shared__ int sidx[4 * RR];

  const int b = blockIdx.x;
  const int g = (b * 171) & 511;
  const int r = threadIdx.x >> 6;
  const int lane = threadIdx.x & 63;
  const int nb = g << 2;

  // 4 wave-uniform pred boxes (fully unrolled -> registers)
  float bx1[4], bx2[4], by1[4], by2[4], a1e[4];
#pragma unroll
  for (int i = 0; i < 4; ++i) {
    float4 pb = *reinterpret_cast<const float4*>(pred + (size_t)(nb + i) * CC);
    bx1[i] = fmaf(-0.5f, pb.z, pb.x);
    bx2[i] = fmaf(0.5f, pb.z, pb.x);
    by1[i] = fmaf(-0.5f, pb.w, pb.y);
    by2[i] = fmaf(0.5f, pb.w, pb.y);
    a1e[i] = pb.z * pb.w + IEPS;
  }

  const float4* __restrict__ dp =
      reinterpret_cast<const float4*>(dpreds + (size_t)r * MM * 4);

  int f0 = FINF, f1 = FINF, f2 = FINF, f3 = FINF;
  float4 cur = dp[lane];
  for (int m0 = 0; m0 < MM; m0 += 64) {
    // prefetch next chunk (one load in flight across the exit branch)
    float4 nxt = cur;
    if (m0 + 64 < MM) nxt = dp[m0 + 64 + lane];

    // per-lane m-box derived values, shared by the 4 n-tests
    float x1 = fmaf(-0.5f, cur.z, cur.x), x2 = fmaf(0.5f, cur.z, cur.x);
    float y1 = fmaf(-0.5f, cur.w, cur.y), y2 = fmaf(0.5f, cur.w, cur.y);
    float a2 = cur.z * cur.w;

#define TEST(i, f)                                                          \
    {                                                                       \
      float iw = fmaxf(fminf(bx2[i], x2) - fmaxf(bx1[i], x1), 0.0f);        \
      float ih = fmaxf(fminf(by2[i], y2) - fmaxf(by1[i], y1), 0.0f);        \
      float inter = iw * ih;                                                \
      float t = a2 + a1e[i];                                                \
      unsigned long long bal = __ballot(3.0f * inter > t);                  \
      int cand = bal ? (m0 + __ffsll(bal) - 1) : FINF;                      \
      f = min(f, cand);                                                     \
    }
    TEST(0, f0) TEST(1, f1) TEST(2, f2) TEST(3, f3)
#undef TEST

    if (max(max(f0, f1), max(f2, f3)) != FINF) break;  // all 4 found
    cur = nxt;
  }
  if (lane == 0) {
    sidx[0 * RR + r] = f0;
    sidx[1 * RR + r] = f1;
    sidx[2 * RR + r] = f2;
    sidx[3 * RR + r] = f3;
  }
  __syncthreads();

  // ---- Entropy epilogue: waves 0..3, wave w handles n = nb + w ----
  if (r < 4) {
    int idxs[RR];
    bool anym = false;
#pragma unroll
    for (int q = 0; q < RR; ++q) {
      idxs[q] = sidx[r * RR + q];
      anym = anym || (idxs[q] < MM);
    }

    const bool has_hi = (lane + 64) < CC;  // lanes 0..19 carry a 2nd class
    float e0 = 0.0f, e1 = 0.0f;
#pragma unroll
    for (int q = 0; q < RR; ++q) {
      if (idxs[q] < MM) {
        const float* row = confs + ((size_t)q * MM + (size_t)idxs[q]) * CC;
        float p0 = row[lane];
        e0 -= p0 * __logf(p0);
        if (has_hi) {
          float p1 = row[lane + 64];
          e1 -= p1 * __logf(p1);
        }
      }
    }

    float maxE = fmaxf(e0, has_hi ? e1 : -INFINITY);
    float minE = fminf(e0, has_hi ? e1 : INFINITY);
#pragma unroll
    for (int o = 32; o >= 1; o >>= 1) {
      maxE = fmaxf(maxE, __shfl_xor(maxE, o));
      minE = fminf(minE, __shfl_xor(minE, o));
    }
    float s = __expf(e0 - maxE) + (has_hi ? __expf(e1 - maxE) : 0.0f);
#pragma unroll
    for (int o = 32; o >= 1; o >>= 1) s += __shfl_xor(s, o);

    float result = anym ? (1.0f - __expf(minE - maxE) / s) : nanf("");
    if (lane == 0) out[nb + r] = result;
  }
}

extern "C" void kernel_launch(void* const* d_in, const int* in_sizes, int n_in,
                              void* d_out, int out_size, void* d_ws, size_t ws_size,
                              hipStream_t stream) {
  const float* pred   = (const float*)d_in[0];   // (N, 84)
  const float* dpreds = (const float*)d_in[1];   // (R, M, 4)
  const float* confs  = (const float*)d_in[2];   // (R, M, 84)
  float* out = (float*)d_out;                    // (N,)

  fused_kernel<<<NN / 4, 640, 0, stream>>>(pred, dpreds, confs, out);
}

// Round 9
// 23.111 us; speedup vs baseline: 1.0983x; 1.0983x over previous
//
#include <hip/hip_runtime.h>
#include <math.h>

#define NN 2048
#define RR 10
#define MM 2048
#define CC 84
#define IEPS 1e-7f

// Kernel 1: one wave (64 lanes) per (n, r) pair. Scan m in chunks of 256
// (4 x 64 independent loads in flight), ballot on hit, first set bit in
// m-order = first match (argmax-of-bool semantics). Division-free compare:
// inter/(a1+a2-inter+eps) > 0.5  <=>  3*inter > a1+a2+eps.
// [R2 configuration: empirically best at 23.1 us. R3-R8 established that
//  work reduction (4x), L2-traffic reduction (10x), dispatch fusion (3->1),
//  prefetch, and load-balance remaps are all null: the timed window is
//  dominated by a ~20-22 us launch/replay floor, kernel GPU time ~3-6 us.]
__global__ __launch_bounds__(256) void match_kernel(
    const float* __restrict__ pred,
    const float* __restrict__ dpreds,
    int* __restrict__ first_idx) {
  int wid = (blockIdx.x * blockDim.x + threadIdx.x) >> 6;
  int lane = threadIdx.x & 63;
  if (wid >= NN * RR) return;
  int n = wid / RR;
  int r = wid - n * RR;

  // pred row stride = 84 floats = 336 B (16B-aligned) -> float4 load OK
  float4 pb = *reinterpret_cast<const float4*>(pred + (size_t)n * CC);
  const float b1x1 = fmaf(-0.5f, pb.z, pb.x), b1x2 = fmaf(0.5f, pb.z, pb.x);
  const float b1y1 = fmaf(-0.5f, pb.w, pb.y), b1y2 = fmaf(0.5f, pb.w, pb.y);
  const float a1e = pb.z * pb.w + IEPS;  // area1 + eps

  const float4* __restrict__ dp =
      reinterpret_cast<const float4*>(dpreds + (size_t)r * MM * 4);

  int found = -1;
  for (int m0 = 0; m0 < MM; m0 += 256) {
    // 4 independent 16B loads in flight
    float4 d0 = dp[m0 + lane];
    float4 d1 = dp[m0 + 64 + lane];
    float4 d2 = dp[m0 + 128 + lane];
    float4 d3 = dp[m0 + 192 + lane];

#define HIT(db, h)                                                          \
    {                                                                       \
      float x1 = fmaf(-0.5f, db.z, db.x), x2 = fmaf(0.5f, db.z, db.x);      \
      float y1 = fmaf(-0.5f, db.w, db.y), y2 = fmaf(0.5f, db.w, db.y);      \
      float iw = fmaxf(fminf(b1x2, x2) - fmaxf(b1x1, x1), 0.0f);            \
      float ih = fmaxf(fminf(b1y2, y2) - fmaxf(b1y1, y1), 0.0f);            \
      float inter = iw * ih;                                                \
      float t = db.z * db.w + a1e; /* a2 + a1 + eps */                      \
      h = (3.0f * inter > t);                                               \
    }
    bool h0, h1, h2, h3;
    HIT(d0, h0) HIT(d1, h1) HIT(d2, h2) HIT(d3, h3)
#undef HIT

    unsigned long long b0 = __ballot(h0);
    unsigned long long b1 = __ballot(h1);
    unsigned long long b2 = __ballot(h2);
    unsigned long long b3 = __ballot(h3);
    if (b0 | b1 | b2 | b3) {
      if (b0)      found = m0 +       (__ffsll(b0) - 1);
      else if (b1) found = m0 + 64  + (__ffsll(b1) - 1);
      else if (b2) found = m0 + 128 + (__ffsll(b2) - 1);
      else         found = m0 + 192 + (__ffsll(b3) - 1);
      break;
    }
  }
  if (lane == 0) first_idx[wid] = found;
}

// Kernel 2: one wave per n. Lane l handles classes l and l+64 (C=84).
// entropy[c] = sum_r -p log p over matched r; softmax over c; out = 1 - min(sm).
__global__ __launch_bounds__(256) void entropy_kernel(
    const float* __restrict__ confs,
    const int* __restrict__ first_idx,
    float* __restrict__ out) {
  int lane = threadIdx.x & 63;
  int n = blockIdx.x * (blockDim.x >> 6) + (threadIdx.x >> 6);
  if (n >= NN) return;

  int idxs[RR];
  bool anym = false;
#pragma unroll
  for (int r = 0; r < RR; ++r) {
    idxs[r] = first_idx[n * RR + r];
    anym = anym || (idxs[r] >= 0);
  }

  const bool has_hi = (lane + 64) < CC;  // lanes 0..19 carry a 2nd class
  float e0 = 0.0f, e1 = 0.0f;
#pragma unroll
  for (int r = 0; r < RR; ++r) {
    if (idxs[r] >= 0) {
      const float* row = confs + ((size_t)r * MM + (size_t)idxs[r]) * CC;
      float p0 = row[lane];
      e0 -= p0 * __logf(p0);
      if (has_hi) {
        float p1 = row[lane + 64];
        e1 -= p1 * __logf(p1);
      }
    }
  }

  float maxE = fmaxf(e0, has_hi ? e1 : -INFINITY);
  float minE = fminf(e0, has_hi ? e1 : INFINITY);
#pragma unroll
  for (int off = 32; off >= 1; off >>= 1) {
    maxE = fmaxf(maxE, __shfl_xor(maxE, off));
    minE = fminf(minE, __shfl_xor(minE, off));
  }
  float s = __expf(e0 - maxE) + (has_hi ? __expf(e1 - maxE) : 0.0f);
#pragma unroll
  for (int off = 32; off >= 1; off >>= 1) s += __shfl_xor(s, off);

  float result = anym ? (1.0f - __expf(minE - maxE) / s) : nanf("");
  if (lane == 0) out[n] = result;
}

extern "C" void kernel_launch(void* const* d_in, const int* in_sizes, int n_in,
                              void* d_out, int out_size, void* d_ws, size_t ws_size,
                              hipStream_t stream) {
  const float* pred   = (const float*)d_in[0];   // (N, 84)
  const float* dpreds = (const float*)d_in[1];   // (R, M, 4)
  const float* confs  = (const float*)d_in[2];   // (R, M, 84)
  float* out = (float*)d_out;                    // (N,)
  int* first_idx = (int*)d_ws;                   // N*R ints

  // Kernel 1: N*R waves, 4 waves/block
  {
    int total_waves = NN * RR;                   // 20480
    int blocks = (total_waves * 64 + 255) / 256; // 5120
    match_kernel<<<blocks, 256, 0, stream>>>(pred, dpreds, first_idx);
  }
  // Kernel 2: one wave per n, 4 waves/block
  {
    int blocks = (NN + 3) / 4;                   // 512
    entropy_kernel<<<blocks, 256, 0, stream>>>(confs, first_idx, out);
  }
}